// Round 1
// baseline (625.066 us; speedup 1.0000x reference)
//
#include <hip/hip_runtime.h>
#include <math.h>

#define N_SEG 50000
#define D     128
#define K2    256   // 2*D pooled width
#define NOUT  128
#define TR    128   // rows per gemm block
#define KT    32    // k-tile
#define LDSW  36    // padded LDS leading dim (multiple of 4 for b128 alignment)

// Kernel 0: mark segment starts. ids sorted, every segment in [0,N) non-empty.
__global__ __launch_bounds__(256) void k_bounds(const int* __restrict__ ids,
                                                int* __restrict__ row_start, int M) {
    int m = blockIdx.x * 256 + threadIdx.x;
    if (m >= M) return;
    int s = ids[m];
    if (m == 0) {
        row_start[s] = 0;
        row_start[N_SEG] = M;
    } else if (ids[m - 1] != s) {
        row_start[s] = m;
    }
}

// Kernel 1: per-segment max + mean. One wave (64 lanes) per segment:
// 2 rows x 32 float4-lanes -> 16B/lane coalesced loads, 1KB/row-pair/instr.
__global__ __launch_bounds__(256) void k_segpool(const float* __restrict__ lane_enc,
                                                 const int* __restrict__ row_start,
                                                 float* __restrict__ pooled) {
    int wid  = threadIdx.x >> 6;
    int lid  = threadIdx.x & 63;
    int s    = blockIdx.x * 4 + wid;
    if (s >= N_SEG) return;
    int start = row_start[s];
    int end   = row_start[s + 1];
    int half  = lid >> 5;   // which row of the pair
    int c4    = lid & 31;   // which float4 of the 128-col row

    float4 vmax = make_float4(-INFINITY, -INFINITY, -INFINITY, -INFINITY);
    float4 vsum = make_float4(0.f, 0.f, 0.f, 0.f);
    for (int r = start + half; r < end; r += 2) {
        const float4 v = *((const float4*)(lane_enc + (size_t)r * D) + c4);
        vmax.x = fmaxf(vmax.x, v.x); vmax.y = fmaxf(vmax.y, v.y);
        vmax.z = fmaxf(vmax.z, v.z); vmax.w = fmaxf(vmax.w, v.w);
        vsum.x += v.x; vsum.y += v.y; vsum.z += v.z; vsum.w += v.w;
    }
    // merge the two row-halves (lane ^ 32)
    vmax.x = fmaxf(vmax.x, __shfl_xor(vmax.x, 32));
    vmax.y = fmaxf(vmax.y, __shfl_xor(vmax.y, 32));
    vmax.z = fmaxf(vmax.z, __shfl_xor(vmax.z, 32));
    vmax.w = fmaxf(vmax.w, __shfl_xor(vmax.w, 32));
    vsum.x += __shfl_xor(vsum.x, 32);
    vsum.y += __shfl_xor(vsum.y, 32);
    vsum.z += __shfl_xor(vsum.z, 32);
    vsum.w += __shfl_xor(vsum.w, 32);

    if (half == 0) {
        int cnt = end - start;
        float4 vmean;
        if (cnt > 0) {
            float inv = 1.0f / (float)cnt;
            vmean = make_float4(vsum.x * inv, vsum.y * inv, vsum.z * inv, vsum.w * inv);
        } else {  // cannot happen by construction; keep output finite
            vmax  = make_float4(0.f, 0.f, 0.f, 0.f);
            vmean = make_float4(0.f, 0.f, 0.f, 0.f);
        }
        *((float4*)(pooled + (size_t)s * K2) + c4)     = vmax;
        *((float4*)(pooled + (size_t)s * K2 + D) + c4) = vmean;
    }
}

// Kernel 2: out = relu(pooled @ W^T + b). 256 threads do a 128x128 tile,
// K staged through LDS in 32-wide tiles, 8x8 register blocking per thread.
__global__ __launch_bounds__(256) void k_gemm(const float* __restrict__ pooled,
                                              const float* __restrict__ W,
                                              const float* __restrict__ bias,
                                              float* __restrict__ out) {
    __shared__ float Pt[TR * LDSW];
    __shared__ float Wt[NOUT * LDSW];
    const int tid = threadIdx.x;
    const int rowbase = blockIdx.x * TR;
    const int tx = tid & 15;   // output group
    const int ty = tid >> 4;   // row group

    float acc[8][8];
#pragma unroll
    for (int i = 0; i < 8; ++i)
#pragma unroll
        for (int j = 0; j < 8; ++j) acc[i][j] = 0.f;

    for (int kt = 0; kt < K2; kt += KT) {
        // stage Pt (128x32) and Wt (128x32); 1024 float4 slots each
#pragma unroll
        for (int j = 0; j < 4; ++j) {
            int slot = tid + 256 * j;
            int row  = slot >> 3;   // 8 float4 per row
            int c4   = slot & 7;
            int grow = rowbase + row;
            if (grow >= N_SEG) grow = N_SEG - 1;
            float4 v = *((const float4*)(pooled + (size_t)grow * K2 + kt) + c4);
            *((float4*)&Pt[row * LDSW + c4 * 4]) = v;
            float4 wv = *((const float4*)(W + (size_t)row * K2 + kt) + c4);
            *((float4*)&Wt[row * LDSW + c4 * 4]) = wv;
        }
        __syncthreads();
#pragma unroll
        for (int g = 0; g < KT / 4; ++g) {
            float4 w[8];
#pragma unroll
            for (int oi = 0; oi < 8; ++oi)
                w[oi] = *((const float4*)&Wt[(tx + 16 * oi) * LDSW + g * 4]);
#pragma unroll
            for (int ri = 0; ri < 8; ++ri) {
                float4 a = *((const float4*)&Pt[(ty + 16 * ri) * LDSW + g * 4]);
#pragma unroll
                for (int oi = 0; oi < 8; ++oi) {
                    acc[ri][oi] = fmaf(a.x, w[oi].x, acc[ri][oi]);
                    acc[ri][oi] = fmaf(a.y, w[oi].y, acc[ri][oi]);
                    acc[ri][oi] = fmaf(a.z, w[oi].z, acc[ri][oi]);
                    acc[ri][oi] = fmaf(a.w, w[oi].w, acc[ri][oi]);
                }
            }
        }
        __syncthreads();
    }

    // epilogue: bias + relu
#pragma unroll
    for (int ri = 0; ri < 8; ++ri) {
        int r = rowbase + ty + 16 * ri;
        if (r < N_SEG) {
#pragma unroll
            for (int oi = 0; oi < 8; ++oi) {
                int o = tx + 16 * oi;
                float v = acc[ri][oi] + bias[o];
                out[(size_t)r * NOUT + o] = fmaxf(v, 0.f);
            }
        }
    }
}

extern "C" void kernel_launch(void* const* d_in, const int* in_sizes, int n_in,
                              void* d_out, int out_size, void* d_ws, size_t ws_size,
                              hipStream_t stream) {
    // inputs: 0 obs_encoding(N,128) f32 [unused], 1 lane_encoding(M,128) f32,
    //         2 same_obs_mask(M,1) int, 3 W(128,256) f32, 4 b(128,) f32
    const float* lane_enc = (const float*)d_in[1];
    const int*   ids      = (const int*)d_in[2];
    const float* W        = (const float*)d_in[3];
    const float* bias     = (const float*)d_in[4];
    float*       out      = (float*)d_out;
    const int M = in_sizes[2];   // 800000

    float* pooled    = (float*)d_ws;                                   // N*256 f32 = 51.2 MB
    int*   row_start = (int*)((char*)d_ws + (size_t)N_SEG * K2 * 4);   // N+1 ints

    k_bounds<<<(M + 255) / 256, 256, 0, stream>>>(ids, row_start, M);
    k_segpool<<<(N_SEG + 3) / 4, 256, 0, stream>>>(lane_enc, row_start, pooled);
    k_gemm<<<(N_SEG + TR - 1) / TR, 256, 0, stream>>>(pooled, W, bias, out);
}

// Round 2
// 598.935 us; speedup vs baseline: 1.0436x; 1.0436x over previous
//
#include <hip/hip_runtime.h>
#include <math.h>

#define N_SEG 50000
#define D     128
#define K2    256   // 2*D pooled width
#define NOUT  128
#define TR    128   // rows per gemm block
#define KT    32    // k-tile
#define LDSW  36    // padded LDS leading dim (multiple of 4 for b128 alignment)

typedef float f4 __attribute__((ext_vector_type(4)));

// Kernel 0: mark segment starts. ids sorted, every segment in [0,N) non-empty.
__global__ __launch_bounds__(256) void k_bounds(const int* __restrict__ ids,
                                                int* __restrict__ row_start, int M) {
    int m = blockIdx.x * 256 + threadIdx.x;
    if (m >= M) return;
    int s = ids[m];
    if (m == 0) {
        row_start[s] = 0;
        row_start[N_SEG] = M;
    } else if (ids[m - 1] != s) {
        row_start[s] = m;
    }
}

// Kernel 1: per-segment max + mean. One wave per segment: 2 rows x 32
// float4-lanes (16B/lane, 1KB/instr). Manual unroll-by-4 keeps 4 independent
// global_load_dwordx4 in flight per wave (MLP vs ~900cyc HBM latency).
__global__ __launch_bounds__(256) void k_segpool(const float* __restrict__ lane_enc,
                                                 const int* __restrict__ row_start,
                                                 float* __restrict__ pooled) {
    int wid  = threadIdx.x >> 6;
    int lid  = threadIdx.x & 63;
    int s    = blockIdx.x * 4 + wid;
    if (s >= N_SEG) return;
    int start = row_start[s];
    int end   = row_start[s + 1];
    int half  = lid >> 5;   // which row of the pair
    int c4    = lid & 31;   // which float4 of the 128-col row

    const f4* base = (const f4*)lane_enc;   // 32 f4 per row
    f4 vmax = { -INFINITY, -INFINITY, -INFINITY, -INFINITY };
    f4 vsum = { 0.f, 0.f, 0.f, 0.f };

    int r = start + half;
    // 4 loads in flight: rows r, r+2, r+4, r+6 for this half
    for (; r + 6 < end; r += 8) {
        f4 v0 = __builtin_nontemporal_load(&base[(size_t)r       * 32 + c4]);
        f4 v1 = __builtin_nontemporal_load(&base[(size_t)(r + 2) * 32 + c4]);
        f4 v2 = __builtin_nontemporal_load(&base[(size_t)(r + 4) * 32 + c4]);
        f4 v3 = __builtin_nontemporal_load(&base[(size_t)(r + 6) * 32 + c4]);
        f4 m01 = __builtin_elementwise_max(v0, v1);
        f4 m23 = __builtin_elementwise_max(v2, v3);
        vmax = __builtin_elementwise_max(vmax, __builtin_elementwise_max(m01, m23));
        vsum += (v0 + v1) + (v2 + v3);
    }
    for (; r < end; r += 2) {
        f4 v = __builtin_nontemporal_load(&base[(size_t)r * 32 + c4]);
        vmax = __builtin_elementwise_max(vmax, v);
        vsum += v;
    }

    // merge the two row-halves (lane ^ 32)
#pragma unroll
    for (int comp = 0; comp < 4; ++comp) {
        float m  = __shfl_xor(vmax[comp], 32);
        float su = __shfl_xor(vsum[comp], 32);
        vmax[comp] = fmaxf(vmax[comp], m);
        vsum[comp] += su;
    }

    if (half == 0) {
        int cnt = end - start;   // >=1 by construction (ids contain arange(N))
        float inv = 1.0f / (float)cnt;
        f4 vmean = vsum * inv;
        *((f4*)(pooled + (size_t)s * K2) + c4)     = vmax;
        *((f4*)(pooled + (size_t)s * K2 + D) + c4) = vmean;
    }
}

// Kernel 2: out = relu(pooled @ W^T + b). 256 threads do a 128x128 tile,
// K staged through LDS in 32-wide tiles, 8x8 register blocking per thread.
__global__ __launch_bounds__(256) void k_gemm(const float* __restrict__ pooled,
                                              const float* __restrict__ W,
                                              const float* __restrict__ bias,
                                              float* __restrict__ out) {
    __shared__ float Pt[TR * LDSW];
    __shared__ float Wt[NOUT * LDSW];
    const int tid = threadIdx.x;
    const int rowbase = blockIdx.x * TR;
    const int tx = tid & 15;   // output group
    const int ty = tid >> 4;   // row group

    float acc[8][8];
#pragma unroll
    for (int i = 0; i < 8; ++i)
#pragma unroll
        for (int j = 0; j < 8; ++j) acc[i][j] = 0.f;

    for (int kt = 0; kt < K2; kt += KT) {
        // stage Pt (128x32) and Wt (128x32); 1024 float4 slots each
#pragma unroll
        for (int j = 0; j < 4; ++j) {
            int slot = tid + 256 * j;
            int row  = slot >> 3;   // 8 float4 per row
            int c4   = slot & 7;
            int grow = rowbase + row;
            if (grow >= N_SEG) grow = N_SEG - 1;
            float4 v = *((const float4*)(pooled + (size_t)grow * K2 + kt) + c4);
            *((float4*)&Pt[row * LDSW + c4 * 4]) = v;
            float4 wv = *((const float4*)(W + (size_t)row * K2 + kt) + c4);
            *((float4*)&Wt[row * LDSW + c4 * 4]) = wv;
        }
        __syncthreads();
#pragma unroll
        for (int g = 0; g < KT / 4; ++g) {
            float4 w[8];
#pragma unroll
            for (int oi = 0; oi < 8; ++oi)
                w[oi] = *((const float4*)&Wt[(tx + 16 * oi) * LDSW + g * 4]);
#pragma unroll
            for (int ri = 0; ri < 8; ++ri) {
                float4 a = *((const float4*)&Pt[(ty + 16 * ri) * LDSW + g * 4]);
#pragma unroll
                for (int oi = 0; oi < 8; ++oi) {
                    acc[ri][oi] = fmaf(a.x, w[oi].x, acc[ri][oi]);
                    acc[ri][oi] = fmaf(a.y, w[oi].y, acc[ri][oi]);
                    acc[ri][oi] = fmaf(a.z, w[oi].z, acc[ri][oi]);
                    acc[ri][oi] = fmaf(a.w, w[oi].w, acc[ri][oi]);
                }
            }
        }
        __syncthreads();
    }

    // epilogue: bias + relu
#pragma unroll
    for (int ri = 0; ri < 8; ++ri) {
        int r = rowbase + ty + 16 * ri;
        if (r < N_SEG) {
#pragma unroll
            for (int oi = 0; oi < 8; ++oi) {
                int o = tx + 16 * oi;
                float v = acc[ri][oi] + bias[o];
                out[(size_t)r * NOUT + o] = fmaxf(v, 0.f);
            }
        }
    }
}

extern "C" void kernel_launch(void* const* d_in, const int* in_sizes, int n_in,
                              void* d_out, int out_size, void* d_ws, size_t ws_size,
                              hipStream_t stream) {
    // inputs: 0 obs_encoding(N,128) f32 [unused], 1 lane_encoding(M,128) f32,
    //         2 same_obs_mask(M,1) int, 3 W(128,256) f32, 4 b(128,) f32
    const float* lane_enc = (const float*)d_in[1];
    const int*   ids      = (const int*)d_in[2];
    const float* W        = (const float*)d_in[3];
    const float* bias     = (const float*)d_in[4];
    float*       out      = (float*)d_out;
    const int M = in_sizes[2];   // 800000

    float* pooled    = (float*)d_ws;                                   // N*256 f32 = 51.2 MB
    int*   row_start = (int*)((char*)d_ws + (size_t)N_SEG * K2 * 4);   // N+1 ints

    k_bounds<<<(M + 255) / 256, 256, 0, stream>>>(ids, row_start, M);
    k_segpool<<<(N_SEG + 3) / 4, 256, 0, stream>>>(lane_enc, row_start, pooled);
    k_gemm<<<(N_SEG + TR - 1) / TR, 256, 0, stream>>>(pooled, W, bias, out);
}